// Round 18
// baseline (401.514 us; speedup 1.0000x reference)
//
#include <hip/hip_runtime.h>
#include <hip/hip_bf16.h>

typedef __attribute__((ext_vector_type(8))) short bf16x8;
typedef __attribute__((ext_vector_type(4))) float f32x4;

constexpr int Bc = 4, Sc = 2048, Dc = 512, Hc = 4;
constexpr float SCALE = 0.044194173824159216f; // 1/sqrt(512)

__device__ __forceinline__ unsigned short f2bf(float f) {
  union { float f; unsigned u; } v; v.f = f;
  unsigned r = v.u + 0x7fffu + ((v.u >> 16) & 1u);
  return (unsigned short)(r >> 16);
}

#define GLD16(GP, LP) __builtin_amdgcn_global_load_lds( \
    (const __attribute__((address_space(1))) unsigned int*)(GP), \
    (__attribute__((address_space(3))) unsigned int*)(LP), 16, 0, 0)

// ---------------- f32 -> bf16 convert (+scale) ----------------
__global__ __launch_bounds__(256) void k_cvt(const float* __restrict__ x,
                                             unsigned short* __restrict__ y, int n4,
                                             float scale) {
  int i = blockIdx.x * 256 + threadIdx.x;
  if (i < n4) {
    float4 v = ((const float4*)x)[i];
    ushort4 o;
    o.x = f2bf(v.x * scale); o.y = f2bf(v.y * scale);
    o.z = f2bf(v.z * scale); o.w = f2bf(v.w * scale);
    ((ushort4*)y)[i] = o;
  }
}

// ---------------- zero-fill f32 ----------------
__global__ __launch_bounds__(256) void k_zero(float* __restrict__ p, int n4) {
  int i = blockIdx.x * 256 + threadIdx.x;
  if (i < n4) ((float4*)p)[i] = float4{0.f, 0.f, 0.f, 0.f};
}

// ---------------- f32 -> bf16 copy (att finalize) ----------------
__global__ __launch_bounds__(256) void k_fin(const float* __restrict__ x,
                                             unsigned short* __restrict__ y, int n4) {
  int i = blockIdx.x * 256 + threadIdx.x;
  if (i < n4) {
    float4 v = ((const float4*)x)[i];
    ushort4 o;
    o.x = f2bf(v.x); o.y = f2bf(v.y); o.z = f2bf(v.z); o.w = f2bf(v.w);
    ((ushort4*)y)[i] = o;
  }
}

// ---------------- FFN2 reduce: out = p0 + p1 + b2[col] + residual ----------------
__global__ __launch_bounds__(256) void k_red(const float* __restrict__ p0,
                                             const float* __restrict__ p1,
                                             const float* __restrict__ res,
                                             const float* __restrict__ b2,
                                             float* __restrict__ out, int n4) {
  int i = blockIdx.x * 256 + threadIdx.x;
  if (i < n4) {
    const int col = (i * 4) & 511;          // Dc=512, 4 | 512 -> in-row
    const float4 a = ((const float4*)p0)[i];
    const float4 b = ((const float4*)p1)[i];
    const float4 r = ((const float4*)res)[i];
    const float4 bb = *(const float4*)(b2 + col);
    float4 o;
    o.x = a.x + b.x + r.x + bb.x;
    o.y = a.y + b.y + r.y + bb.y;
    o.z = a.z + b.z + r.z + bb.z;
    o.w = a.w + b.w + r.w + bb.w;
    ((float4*)out)[i] = o;
  }
}

// ---------------- weight transpose + convert ----------------
__global__ __launch_bounds__(256) void k_wt(const float* __restrict__ W,
                                            unsigned short* __restrict__ WT,
                                            int K_, int N_, float scale) {
  const int z = blockIdx.z;
  W  += (size_t)z * K_ * N_;
  WT += (size_t)z * K_ * N_;
  __shared__ float t[32][33];
  const int k0 = blockIdx.x * 32, n0 = blockIdx.y * 32;
  const int tx = threadIdx.x & 31, ty = threadIdx.x >> 5;
#pragma unroll
  for (int i = 0; i < 32; i += 8) t[ty + i][tx] = W[(size_t)(k0 + ty + i) * N_ + n0 + tx];
  __syncthreads();
#pragma unroll
  for (int i = 0; i < 32; i += 8)
    WT[(size_t)(n0 + ty + i) * K_ + k0 + tx] = f2bf(t[tx][ty + i] * scale);
}

// ---------------- c[h,d'] = SCALE * sum_e bq[h,e] * Wk[h,d',e] ----------------
__global__ __launch_bounds__(256) void k_vecmat(const float* __restrict__ bqv,
                                                const float* __restrict__ Wk,
                                                float* __restrict__ cvec) {
  const int g = blockIdx.x * 256 + threadIdx.x;  // 2048 = 4h x 512d'
  const int h = g >> 9, d = g & 511;
  const float* wr = Wk + ((size_t)h * 512 + d) * 512;
  const float* bb = bqv + h * 512;
  float s = 0.f;
  for (int e = 0; e < 512; e += 4) {
    const float4 w = *(const float4*)(wr + e);
    const float4 q = *(const float4*)(bb + e);
    s += w.x * q.x + w.y * q.y + w.z * q.z + w.w * q.w;
  }
  cvec[g] = s * SCALE;
}

// ---------------- generalized GEMM: C = (A + z*sA) @ (BT + (z>>bzsh)*sB)^T ----------------
// R11-proven 128^2 2-phase core.
// EPI_MT  : z=h. out bf16 [z][512][512]  (= SCALE * M^T, M = Wq@Wk^T per head)
// EPI_QK  : z=h. Q' = X@(s*M) + c. out Qp[((bb*4+h)*S+s)*D+col], bias=cvec[h*D+col]
// EPI_V   : z=h. V^T. out [((bb*4+h)*D+col)*S+s], bias=bv[h*D+col]
// EPI_EXP : z=bh(pair-local). P[z,row,col]=exp(acc); atomicAdd lbuf[z*S+row]+=rowsum
// EPI_PV  : z=bh. atomicAdd attf[(z>>2)*S*D + row*D+col] += acc*0.25/lbuf[z*S+row]
// EPI_RELU: out bf16 relu(acc+bias)
// EPI_OUTP: z=kc in {0,1}. K-half kc of FFN2 -> fpart[kc][row*512+col] = acc
//           (plain f32 stores to ws; summed with bias+residual by k_red)
enum { EPI_MT = 0, EPI_QK = 1, EPI_V = 2, EPI_EXP = 3, EPI_PV = 4, EPI_RELU = 5, EPI_OUTP = 6 };

template <int EPI>
__global__ __launch_bounds__(256)
void k_gemm(const unsigned short* __restrict__ A, size_t sA,
            const unsigned short* __restrict__ BTg, size_t sB, int bzsh,
            const float* __restrict__ bias,
            void* __restrict__ outv, float* __restrict__ extra, int K)
{
  const int tid = threadIdx.x;
  const int w = tid >> 6, l = tid & 63;
  const int l15 = l & 15, lg = l >> 4;
  const int mb = blockIdx.x * 128, nb = blockIdx.y * 128;
  const int z = blockIdx.z;
  const int h = z;
  const unsigned short* Ae = A + (size_t)((EPI == EPI_OUTP) ? 0 : z) * sA;
  const unsigned short* Be = (EPI == EPI_OUTP) ? BTg
                                               : BTg + (size_t)(z >> bzsh) * sB;
  const int kb0 = (EPI == EPI_OUTP) ? z * 1024 : 0;       // K-half base (elements)
  const int nkt = (EPI == EPI_OUTP) ? 16 : (K >> 6);      // even everywhere

  __shared__ __align__(16) unsigned short As0[128 * 64], As1[128 * 64];
  __shared__ __align__(16) unsigned short Bs0[128 * 64], Bs1[128 * 64];

  f32x4 acc[4][4] = {};
  const int wm = w >> 1, wn = w & 1;
  const int mw = wm * 64, nw = wn * 64;

  auto stage = [&](int kb, unsigned short* Ad, unsigned short* Bd) {
#pragma unroll
    for (int i = 0; i < 4; ++i) {
      const int chunk = (w * 4 + i) * 64 + l;
      const int row = chunk >> 3;
      const int sb = ((chunk & 7) * 16) ^ ((row & 7) << 4);
      GLD16(Ae + (size_t)(mb + row) * K + kb0 + kb + (sb >> 1), (char*)Ad + (w * 4 + i) * 1024);
      GLD16(Be + (size_t)(nb + row) * K + kb0 + kb + (sb >> 1), (char*)Bd + (w * 4 + i) * 1024);
    }
  };
  auto compute = [&](const unsigned short* Asb, const unsigned short* Bsb) {
#pragma unroll
    for (int ks = 0; ks < 2; ++ks) {
      bf16x8 af[4], bfr[4];
#pragma unroll
      for (int m = 0; m < 4; ++m) {
        const int row = mw + m * 16 + l15;
        const int off = (ks * 64 + lg * 16) ^ ((row & 7) << 4);
        af[m] = *(const bf16x8*)((const char*)Asb + row * 128 + off);
      }
#pragma unroll
      for (int n = 0; n < 4; ++n) {
        const int row = nw + n * 16 + l15;
        const int off = (ks * 64 + lg * 16) ^ ((row & 7) << 4);
        bfr[n] = *(const bf16x8*)((const char*)Bsb + row * 128 + off);
      }
#pragma unroll
      for (int m = 0; m < 4; ++m)
#pragma unroll
        for (int n = 0; n < 4; ++n)
          acc[m][n] = __builtin_amdgcn_mfma_f32_16x16x32_bf16(af[m], bfr[n], acc[m][n], 0, 0, 0);
    }
  };

  stage(0, As0, Bs0);
  __syncthreads();
  for (int kt = 0; kt < nkt; kt += 2) {
    if (kt + 1 < nkt) stage((kt + 1) << 6, As1, Bs1);
    compute(As0, Bs0);
    __syncthreads();
    if (kt + 2 < nkt) stage((kt + 2) << 6, As0, Bs0);
    compute(As1, Bs1);
    __syncthreads();
  }

  if constexpr (EPI == EPI_MT) {
    unsigned short* op = (unsigned short*)outv;
#pragma unroll
    for (int m = 0; m < 4; ++m)
#pragma unroll
      for (int n = 0; n < 4; ++n) {
        const int col = nb + nw + n * 16 + l15;
#pragma unroll
        for (int r = 0; r < 4; ++r) {
          const int row = mb + mw + m * 16 + lg * 4 + r;
          op[((size_t)z * 512 + row) * 512 + col] = f2bf(acc[m][n][r]);
        }
      }
  } else if constexpr (EPI == EPI_QK || EPI == EPI_V) {
    unsigned short* op = (unsigned short*)outv;
#pragma unroll
    for (int m = 0; m < 4; ++m) {
#pragma unroll
      for (int n = 0; n < 4; ++n) {
        const int col = nb + nw + n * 16 + l15;
        const float bv = bias[h * Dc + col];
#pragma unroll
        for (int r = 0; r < 4; ++r) {
          const int row = mb + mw + m * 16 + lg * 4 + r;
          const float v = acc[m][n][r] + bv;
          const int bb = row >> 11, s = row & 2047;
          if constexpr (EPI == EPI_QK)
            op[(((size_t)bb * Hc + h) * Sc + s) * Dc + col] = f2bf(v);
          else
            op[(((size_t)bb * Hc + h) * Dc + col) * Sc + s] = f2bf(v);
        }
      }
    }
  } else if constexpr (EPI == EPI_EXP) {
    unsigned short* P = (unsigned short*)outv;
#pragma unroll
    for (int m = 0; m < 4; ++m) {
#pragma unroll
      for (int r = 0; r < 4; ++r) {
        const int row = mb + mw + m * 16 + lg * 4 + r;
        float ps = 0.f;
#pragma unroll
        for (int n = 0; n < 4; ++n) {
          const int col = nb + nw + n * 16 + l15;
          const float p = __expf(acc[m][n][r]);
          ps += p;
          P[((size_t)h * Sc + row) * Sc + col] = f2bf(p);
        }
#pragma unroll
        for (int d = 1; d < 16; d <<= 1) ps += __shfl_xor(ps, d);
        if (l15 == 0) atomicAdd(&extra[h * Sc + row], ps);
      }
    }
  } else if constexpr (EPI == EPI_PV) {
    float* of = (float*)outv + (size_t)(h >> 2) * 1048576;  // pair-local batch
#pragma unroll
    for (int m = 0; m < 4; ++m) {
#pragma unroll
      for (int r = 0; r < 4; ++r) {
        const int row = mb + mw + m * 16 + lg * 4 + r;
        const float il = 0.25f / extra[h * Sc + row];
#pragma unroll
        for (int n = 0; n < 4; ++n) {
          const int col = nb + nw + n * 16 + l15;
          atomicAdd(&of[(size_t)row * Dc + col], acc[m][n][r] * il);
        }
      }
    }
  } else if constexpr (EPI == EPI_RELU) {
#pragma unroll
    for (int m = 0; m < 4; ++m) {
#pragma unroll
      for (int n = 0; n < 4; ++n) {
        const int col = nb + nw + n * 16 + l15;
        const float bv = bias[col];
#pragma unroll
        for (int r = 0; r < 4; ++r) {
          const int row = mb + mw + m * 16 + lg * 4 + r;
          ((unsigned short*)outv)[(size_t)row * 2048 + col] = f2bf(fmaxf(acc[m][n][r] + bv, 0.f));
        }
      }
    }
  } else {  // EPI_OUTP: K-half partial -> ws (plain stores, no atomics)
    float* of = (float*)outv + (size_t)z * 4194304;
#pragma unroll
    for (int m = 0; m < 4; ++m) {
#pragma unroll
      for (int n = 0; n < 4; ++n) {
        const int col = nb + nw + n * 16 + l15;
#pragma unroll
        for (int r = 0; r < 4; ++r) {
          const int row = mb + mw + m * 16 + lg * 4 + r;
          of[(size_t)row * Dc + col] = acc[m][n][r];
        }
      }
    }
  }
}

extern "C" void kernel_launch(void* const* d_in, const int* in_sizes, int n_in,
                              void* d_out, int out_size, void* d_ws, size_t ws_size,
                              hipStream_t stream)
{
  const float* fencs = (const float*)d_in[0];
  const float* Wq  = (const float*)d_in[1];
  const float* bq  = (const float*)d_in[2];
  const float* Wk  = (const float*)d_in[3];
  const float* bk  = (const float*)d_in[4];   // eliminated algebraically (softmax shift-invariance)
  const float* Wv  = (const float*)d_in[5];
  const float* bvv = (const float*)d_in[6];
  const float* W1  = (const float*)d_in[7];
  const float* b1  = (const float*)d_in[8];
  const float* W2  = (const float*)d_in[9];
  const float* b2  = (const float*)d_in[10];
  float* out = (float*)d_out;
  (void)bk;

  // ws layout, ushort elements; total 134,291,456 B <= proven 144,703,488
  if (ws_size < 134291456u) return;
  unsigned short* MTb = (unsigned short*)d_ws;            // [4][512][512]  (s*M^T)
  unsigned short* WvT = MTb + (size_t)1048576;            // [4][512][512]
  unsigned short* W1T = WvT + (size_t)1048576;            // [2048][512]; earlier: Wqs bf16
  unsigned short* W2T = W1T + (size_t)1048576;            // [512][2048]; earlier: Wkb bf16
  unsigned short* Xbf = W2T + (size_t)1048576;            // [4*2048][512]
  unsigned short* Qp  = Xbf + (size_t)4194304;            // [2,4,2048,512] pair; later attb
  unsigned short* VTp = Qp  + (size_t)8388608;            // [2,4,512,2048] pair
  unsigned short* P2  = VTp + (size_t)8388608;            // [8][2048][2048]; later hid+fpart
  float* attf = (float*)(P2 + (size_t)33554432);          // [4,2048,512] f32
  float* lbuf = attf + (size_t)4194304;                   // [8,2048] f32 per pair
  float* cvec = lbuf + (size_t)16384;                     // [4,512] f32
  unsigned short* Wqs  = W1T;                             // transient (dead before W1T built)
  unsigned short* Wkb  = W2T;
  unsigned short* attb = Qp;                              // overlay after pass1(p1)
  unsigned short* hid  = P2;                              // [8192][2048] bf16 = first half of P2
  float* fpart = (float*)(P2 + (size_t)16777216);         // [2][8192*512] f32 = second half

  // input + weight preprocessing
  k_cvt<<<4096, 256, 0, stream>>>(fencs, Xbf, 1048576, 1.0f);
  k_cvt<<<1024, 256, 0, stream>>>(Wq, Wqs, 262144, SCALE);
  k_cvt<<<1024, 256, 0, stream>>>(Wk, Wkb, 262144, 1.0f);
  k_vecmat<<<8, 256, 0, stream>>>(bq, Wk, cvec);
  // MT[h] = Wk_h @ (s*Wq_h)^T   (64 blocks, 0.5 GF)
  k_gemm<EPI_MT><<<dim3(4, 4, 4), 256, 0, stream>>>(
      Wkb, 262144, Wqs, 262144, 0, nullptr, MTb, nullptr, 512);
  k_wt<<<dim3(16, 16, 4), 256, 0, stream>>>(Wv, WvT, 512, 512, 1.0f);
  k_zero<<<4096, 256, 0, stream>>>(attf, 1048576);

  for (int p = 0; p < 2; ++p) {
    const unsigned short* Xp = Xbf + (size_t)p * 2097152;   // pair's 2 batches
    // Q' = X@(s*M) + c  (per pair, 4 heads, M=4096): 512 blocks
    k_gemm<EPI_QK><<<dim3(32, 4, 4), 256, 0, stream>>>(
        Xp, 0, MTb, 262144, 0, cvec, Qp, nullptr, 512);
    // V^T (per pair): 512 blocks
    k_gemm<EPI_V><<<dim3(32, 4, 4), 256, 0, stream>>>(
        Xp, 0, WvT, 262144, 0, bvv, VTp, nullptr, 512);
    k_zero<<<16, 256, 0, stream>>>(lbuf, 4096);
    // pass1 pair: P = exp(Q'@X^T), l = rowsum  (2048 blocks; BT = X itself)
    k_gemm<EPI_EXP><<<dim3(16, 16, 8), 256, 0, stream>>>(
        Qp, 1048576, Xp, 1048576, 2, nullptr, P2, lbuf, 512);
    // pass2 pair: attf += (P@V^T) * 0.25/l  (512 blocks, K=2048)
    k_gemm<EPI_PV><<<dim3(16, 4, 8), 256, 0, stream>>>(
        P2, 4194304, VTp, 1048576, 0, nullptr,
        attf + (size_t)p * 2097152, lbuf, 2048);
  }

  // FFN weights (QKV bf16 scratch now dead)
  k_wt<<<dim3(16, 64, 1), 256, 0, stream>>>(W1, W1T, 512, 2048, 1.0f);
  k_wt<<<dim3(64, 16, 1), 256, 0, stream>>>(W2, W2T, 2048, 512, 1.0f);

  k_fin<<<4096, 256, 0, stream>>>(attf, attb, 1048576);

  k_gemm<EPI_RELU><<<dim3(64, 16, 1), 256, 0, stream>>>(
      attb, 0, W1T, 0, 0, b1, hid, nullptr, 512);
  // FFN2: k-split x2 into ws partials (512 blocks = 2/CU; no d_out atomics),
  // then fused reduce out = p0 + p1 + b2 + residual.
  k_gemm<EPI_OUTP><<<dim3(64, 4, 2), 256, 0, stream>>>(
      hid, 0, W2T, 0, 0, nullptr, fpart, nullptr, 2048);
  k_red<<<4096, 256, 0, stream>>>(fpart, fpart + 4194304, attf, b2, out, 1048576);
}

// Round 19
// 393.334 us; speedup vs baseline: 1.0208x; 1.0208x over previous
//
#include <hip/hip_runtime.h>
#include <hip/hip_bf16.h>

typedef __attribute__((ext_vector_type(8))) short bf16x8;
typedef __attribute__((ext_vector_type(4))) float f32x4;

constexpr int Bc = 4, Sc = 2048, Dc = 512, Hc = 4;
constexpr float SCALE = 0.044194173824159216f; // 1/sqrt(512)

__device__ __forceinline__ unsigned short f2bf(float f) {
  union { float f; unsigned u; } v; v.f = f;
  unsigned r = v.u + 0x7fffu + ((v.u >> 16) & 1u);
  return (unsigned short)(r >> 16);
}

#define GLD16(GP, LP) __builtin_amdgcn_global_load_lds( \
    (const __attribute__((address_space(1))) unsigned int*)(GP), \
    (__attribute__((address_space(3))) unsigned int*)(LP), 16, 0, 0)

// ---------------- f32 -> bf16 convert (+scale) ----------------
__global__ __launch_bounds__(256) void k_cvt(const float* __restrict__ x,
                                             unsigned short* __restrict__ y, int n4,
                                             float scale) {
  int i = blockIdx.x * 256 + threadIdx.x;
  if (i < n4) {
    float4 v = ((const float4*)x)[i];
    ushort4 o;
    o.x = f2bf(v.x * scale); o.y = f2bf(v.y * scale);
    o.z = f2bf(v.z * scale); o.w = f2bf(v.w * scale);
    ((ushort4*)y)[i] = o;
  }
}

// ---------------- zero-fill f32 ----------------
__global__ __launch_bounds__(256) void k_zero(float* __restrict__ p, int n4) {
  int i = blockIdx.x * 256 + threadIdx.x;
  if (i < n4) ((float4*)p)[i] = float4{0.f, 0.f, 0.f, 0.f};
}

// ---------------- f32 -> bf16 copy (att finalize) ----------------
__global__ __launch_bounds__(256) void k_fin(const float* __restrict__ x,
                                             unsigned short* __restrict__ y, int n4) {
  int i = blockIdx.x * 256 + threadIdx.x;
  if (i < n4) {
    float4 v = ((const float4*)x)[i];
    ushort4 o;
    o.x = f2bf(v.x); o.y = f2bf(v.y); o.z = f2bf(v.z); o.w = f2bf(v.w);
    ((ushort4*)y)[i] = o;
  }
}

// ---------------- weight transpose + convert ----------------
__global__ __launch_bounds__(256) void k_wt(const float* __restrict__ W,
                                            unsigned short* __restrict__ WT,
                                            int K_, int N_, float scale) {
  const int z = blockIdx.z;
  W  += (size_t)z * K_ * N_;
  WT += (size_t)z * K_ * N_;
  __shared__ float t[32][33];
  const int k0 = blockIdx.x * 32, n0 = blockIdx.y * 32;
  const int tx = threadIdx.x & 31, ty = threadIdx.x >> 5;
#pragma unroll
  for (int i = 0; i < 32; i += 8) t[ty + i][tx] = W[(size_t)(k0 + ty + i) * N_ + n0 + tx];
  __syncthreads();
#pragma unroll
  for (int i = 0; i < 32; i += 8)
    WT[(size_t)(n0 + ty + i) * K_ + k0 + tx] = f2bf(t[tx][ty + i] * scale);
}

// ---------------- c[h,d'] = SCALE * sum_e bq[h,e] * Wk[h,d',e] ----------------
__global__ __launch_bounds__(256) void k_vecmat(const float* __restrict__ bqv,
                                                const float* __restrict__ Wk,
                                                float* __restrict__ cvec) {
  const int g = blockIdx.x * 256 + threadIdx.x;  // 2048 = 4h x 512d'
  const int h = g >> 9, d = g & 511;
  const float* wr = Wk + ((size_t)h * 512 + d) * 512;
  const float* bb = bqv + h * 512;
  float s = 0.f;
  for (int e = 0; e < 512; e += 4) {
    const float4 w = *(const float4*)(wr + e);
    const float4 q = *(const float4*)(bb + e);
    s += w.x * q.x + w.y * q.y + w.z * q.z + w.w * q.w;
  }
  cvec[g] = s * SCALE;
}

// ---------------- generalized GEMM: C = (A + z*sA) @ (BT + (z>>bzsh)*sB)^T ----------------
// R11/R17-proven 128^2 2-phase core + T1 XCD-chunked tile remap (R19): the
// hardware round-robins linear block ids across the 8 XCDs; remapping tile id
// = (lin%8)*(nwg/8)+lin/8 gives each XCD a CONTIGUOUS tile range (e.g. pass1:
// one (pair,head) => A+B = 4MB = one XCD L2). Bijective since nwg%8==0 for all
// launches here. Pure relabeling — no sync/layout change.
// EPI_MT  : z=h. out bf16 [z][512][512]  (= SCALE * M^T, M = Wq@Wk^T per head)
// EPI_QK  : z=h. Q' = X@(s*M) + c. out Qp[((bb*4+h)*S+s)*D+col], bias=cvec[h*D+col]
// EPI_V   : z=h. V^T. out [((bb*4+h)*D+col)*S+s], bias=bv[h*D+col]
// EPI_EXP : z=bh(pair-local). P[z,row,col]=exp(acc); atomicAdd lbuf[z*S+row]+=rowsum
// EPI_PV  : z=bh. atomicAdd attf[(z>>2)*S*D + row*D+col] += acc*0.25/lbuf[z*S+row]
// EPI_RELU: out bf16 relu(acc+bias)
// EPI_OUT : out f32 acc+bias+extra (residual), direct write
enum { EPI_MT = 0, EPI_QK = 1, EPI_V = 2, EPI_EXP = 3, EPI_PV = 4, EPI_RELU = 5, EPI_OUT = 6 };

template <int EPI>
__global__ __launch_bounds__(256)
void k_gemm(const unsigned short* __restrict__ A, size_t sA,
            const unsigned short* __restrict__ BTg, size_t sB, int bzsh,
            const float* __restrict__ bias,
            void* __restrict__ outv, float* __restrict__ extra, int K)
{
  const int tid = threadIdx.x;
  const int w = tid >> 6, l = tid & 63;
  const int l15 = l & 15, lg = l >> 4;

  // T1 XCD-chunked remap (bijective: nwg % 8 == 0 for every launch below)
  const int Dx = gridDim.x, Dy = gridDim.y;
  const int nwg = Dx * Dy * gridDim.z;
  const int lin = blockIdx.x + Dx * (blockIdx.y + Dy * blockIdx.z);
  const int nid = (lin & 7) * (nwg >> 3) + (lin >> 3);
  const int bx = nid % Dx;
  const int rest = nid / Dx;
  const int by = rest % Dy;
  const int bz = rest / Dy;

  const int mb = bx * 128, nb = by * 128;
  const int z = bz;
  const int h = z;
  const unsigned short* Ae = A + (size_t)z * sA;
  const unsigned short* Be = BTg + (size_t)(z >> bzsh) * sB;

  __shared__ __align__(16) unsigned short As0[128 * 64], As1[128 * 64];
  __shared__ __align__(16) unsigned short Bs0[128 * 64], Bs1[128 * 64];

  f32x4 acc[4][4] = {};
  const int wm = w >> 1, wn = w & 1;
  const int mw = wm * 64, nw = wn * 64;
  const int nkt = K >> 6;   // even in all uses (8 or 32)

  auto stage = [&](int kb, unsigned short* Ad, unsigned short* Bd) {
#pragma unroll
    for (int i = 0; i < 4; ++i) {
      const int chunk = (w * 4 + i) * 64 + l;
      const int row = chunk >> 3;
      const int sb = ((chunk & 7) * 16) ^ ((row & 7) << 4);
      GLD16(Ae + (size_t)(mb + row) * K + kb + (sb >> 1), (char*)Ad + (w * 4 + i) * 1024);
      GLD16(Be + (size_t)(nb + row) * K + kb + (sb >> 1), (char*)Bd + (w * 4 + i) * 1024);
    }
  };
  auto compute = [&](const unsigned short* Asb, const unsigned short* Bsb) {
#pragma unroll
    for (int ks = 0; ks < 2; ++ks) {
      bf16x8 af[4], bfr[4];
#pragma unroll
      for (int m = 0; m < 4; ++m) {
        const int row = mw + m * 16 + l15;
        const int off = (ks * 64 + lg * 16) ^ ((row & 7) << 4);
        af[m] = *(const bf16x8*)((const char*)Asb + row * 128 + off);
      }
#pragma unroll
      for (int n = 0; n < 4; ++n) {
        const int row = nw + n * 16 + l15;
        const int off = (ks * 64 + lg * 16) ^ ((row & 7) << 4);
        bfr[n] = *(const bf16x8*)((const char*)Bsb + row * 128 + off);
      }
#pragma unroll
      for (int m = 0; m < 4; ++m)
#pragma unroll
        for (int n = 0; n < 4; ++n)
          acc[m][n] = __builtin_amdgcn_mfma_f32_16x16x32_bf16(af[m], bfr[n], acc[m][n], 0, 0, 0);
    }
  };

  stage(0, As0, Bs0);
  __syncthreads();
  for (int kt = 0; kt < nkt; kt += 2) {
    if (kt + 1 < nkt) stage((kt + 1) << 6, As1, Bs1);
    compute(As0, Bs0);
    __syncthreads();
    if (kt + 2 < nkt) stage((kt + 2) << 6, As0, Bs0);
    compute(As1, Bs1);
    __syncthreads();
  }

  if constexpr (EPI == EPI_MT) {
    unsigned short* op = (unsigned short*)outv;
#pragma unroll
    for (int m = 0; m < 4; ++m)
#pragma unroll
      for (int n = 0; n < 4; ++n) {
        const int col = nb + nw + n * 16 + l15;
#pragma unroll
        for (int r = 0; r < 4; ++r) {
          const int row = mb + mw + m * 16 + lg * 4 + r;
          op[((size_t)z * 512 + row) * 512 + col] = f2bf(acc[m][n][r]);
        }
      }
  } else if constexpr (EPI == EPI_QK || EPI == EPI_V) {
    unsigned short* op = (unsigned short*)outv;
#pragma unroll
    for (int m = 0; m < 4; ++m) {
#pragma unroll
      for (int n = 0; n < 4; ++n) {
        const int col = nb + nw + n * 16 + l15;
        const float bv = bias[h * Dc + col];
#pragma unroll
        for (int r = 0; r < 4; ++r) {
          const int row = mb + mw + m * 16 + lg * 4 + r;
          const float v = acc[m][n][r] + bv;
          const int bb = row >> 11, s = row & 2047;
          if constexpr (EPI == EPI_QK)
            op[(((size_t)bb * Hc + h) * Sc + s) * Dc + col] = f2bf(v);
          else
            op[(((size_t)bb * Hc + h) * Dc + col) * Sc + s] = f2bf(v);
        }
      }
    }
  } else if constexpr (EPI == EPI_EXP) {
    unsigned short* P = (unsigned short*)outv;
#pragma unroll
    for (int m = 0; m < 4; ++m) {
#pragma unroll
      for (int r = 0; r < 4; ++r) {
        const int row = mb + mw + m * 16 + lg * 4 + r;
        float ps = 0.f;
#pragma unroll
        for (int n = 0; n < 4; ++n) {
          const int col = nb + nw + n * 16 + l15;
          const float p = __expf(acc[m][n][r]);
          ps += p;
          P[((size_t)h * Sc + row) * Sc + col] = f2bf(p);
        }
#pragma unroll
        for (int d = 1; d < 16; d <<= 1) ps += __shfl_xor(ps, d);
        if (l15 == 0) atomicAdd(&extra[h * Sc + row], ps);
      }
    }
  } else if constexpr (EPI == EPI_PV) {
    float* of = (float*)outv + (size_t)(h >> 2) * 1048576;  // pair-local batch
#pragma unroll
    for (int m = 0; m < 4; ++m) {
#pragma unroll
      for (int r = 0; r < 4; ++r) {
        const int row = mb + mw + m * 16 + lg * 4 + r;
        const float il = 0.25f / extra[h * Sc + row];
#pragma unroll
        for (int n = 0; n < 4; ++n) {
          const int col = nb + nw + n * 16 + l15;
          atomicAdd(&of[(size_t)row * Dc + col], acc[m][n][r] * il);
        }
      }
    }
  } else if constexpr (EPI == EPI_RELU) {
#pragma unroll
    for (int m = 0; m < 4; ++m) {
#pragma unroll
      for (int n = 0; n < 4; ++n) {
        const int col = nb + nw + n * 16 + l15;
        const float bv = bias[col];
#pragma unroll
        for (int r = 0; r < 4; ++r) {
          const int row = mb + mw + m * 16 + lg * 4 + r;
          ((unsigned short*)outv)[(size_t)row * 2048 + col] = f2bf(fmaxf(acc[m][n][r] + bv, 0.f));
        }
      }
    }
  } else {  // EPI_OUT
    float* of = (float*)outv;
#pragma unroll
    for (int m = 0; m < 4; ++m) {
#pragma unroll
      for (int n = 0; n < 4; ++n) {
        const int col = nb + nw + n * 16 + l15;
        const float bv = bias[col];
#pragma unroll
        for (int r = 0; r < 4; ++r) {
          const int row = mb + mw + m * 16 + lg * 4 + r;
          of[(size_t)row * Dc + col] = acc[m][n][r] + bv + extra[(size_t)row * Dc + col];
        }
      }
    }
  }
}

extern "C" void kernel_launch(void* const* d_in, const int* in_sizes, int n_in,
                              void* d_out, int out_size, void* d_ws, size_t ws_size,
                              hipStream_t stream)
{
  const float* fencs = (const float*)d_in[0];
  const float* Wq  = (const float*)d_in[1];
  const float* bq  = (const float*)d_in[2];
  const float* Wk  = (const float*)d_in[3];
  const float* bk  = (const float*)d_in[4];   // eliminated algebraically (softmax shift-invariance)
  const float* Wv  = (const float*)d_in[5];
  const float* bvv = (const float*)d_in[6];
  const float* W1  = (const float*)d_in[7];
  const float* b1  = (const float*)d_in[8];
  const float* W2  = (const float*)d_in[9];
  const float* b2  = (const float*)d_in[10];
  float* out = (float*)d_out;
  (void)bk;

  // ws layout, ushort elements; total 134,291,456 B <= proven 144,703,488
  if (ws_size < 134291456u) return;
  unsigned short* MTb = (unsigned short*)d_ws;            // [4][512][512]  (s*M^T)
  unsigned short* WvT = MTb + (size_t)1048576;            // [4][512][512]
  unsigned short* W1T = WvT + (size_t)1048576;            // [2048][512]; earlier: Wqs bf16
  unsigned short* W2T = W1T + (size_t)1048576;            // [512][2048]; earlier: Wkb bf16
  unsigned short* Xbf = W2T + (size_t)1048576;            // [4*2048][512]
  unsigned short* Qp  = Xbf + (size_t)4194304;            // [2,4,2048,512] pair; later attb
  unsigned short* VTp = Qp  + (size_t)8388608;            // [2,4,512,2048] pair
  unsigned short* P2  = VTp + (size_t)8388608;            // [8][2048][2048]; later hid
  float* attf = (float*)(P2 + (size_t)33554432);          // [4,2048,512] f32
  float* lbuf = attf + (size_t)4194304;                   // [8,2048] f32 per pair
  float* cvec = lbuf + (size_t)16384;                     // [4,512] f32
  unsigned short* Wqs  = W1T;                             // transient (dead before W1T built)
  unsigned short* Wkb  = W2T;
  unsigned short* attb = Qp;                              // overlay after pass1(p1)
  unsigned short* hid  = P2;                              // overlay after pass2(p1)

  // input + weight preprocessing
  k_cvt<<<4096, 256, 0, stream>>>(fencs, Xbf, 1048576, 1.0f);
  k_cvt<<<1024, 256, 0, stream>>>(Wq, Wqs, 262144, SCALE);
  k_cvt<<<1024, 256, 0, stream>>>(Wk, Wkb, 262144, 1.0f);
  k_vecmat<<<8, 256, 0, stream>>>(bq, Wk, cvec);
  // MT[h] = Wk_h @ (s*Wq_h)^T   (64 blocks, 0.5 GF)
  k_gemm<EPI_MT><<<dim3(4, 4, 4), 256, 0, stream>>>(
      Wkb, 262144, Wqs, 262144, 0, nullptr, MTb, nullptr, 512);
  k_wt<<<dim3(16, 16, 4), 256, 0, stream>>>(Wv, WvT, 512, 512, 1.0f);
  k_zero<<<4096, 256, 0, stream>>>(attf, 1048576);

  for (int p = 0; p < 2; ++p) {
    const unsigned short* Xp = Xbf + (size_t)p * 2097152;   // pair's 2 batches
    // Q' = X@(s*M) + c  (per pair, 4 heads, M=4096): 512 blocks
    k_gemm<EPI_QK><<<dim3(32, 4, 4), 256, 0, stream>>>(
        Xp, 0, MTb, 262144, 0, cvec, Qp, nullptr, 512);
    // V^T (per pair): 512 blocks
    k_gemm<EPI_V><<<dim3(32, 4, 4), 256, 0, stream>>>(
        Xp, 0, WvT, 262144, 0, bvv, VTp, nullptr, 512);
    k_zero<<<16, 256, 0, stream>>>(lbuf, 4096);
    // pass1 pair: P = exp(Q'@X^T), l = rowsum  (2048 blocks; BT = X itself)
    k_gemm<EPI_EXP><<<dim3(16, 16, 8), 256, 0, stream>>>(
        Qp, 1048576, Xp, 1048576, 2, nullptr, P2, lbuf, 512);
    // pass2 pair: attf += (P@V^T) * 0.25/l  (512 blocks, K=2048)
    k_gemm<EPI_PV><<<dim3(16, 4, 8), 256, 0, stream>>>(
        P2, 4194304, VTp, 1048576, 0, nullptr,
        attf + (size_t)p * 2097152, lbuf, 2048);
  }

  // FFN weights (QKV bf16 scratch now dead)
  k_wt<<<dim3(16, 64, 1), 256, 0, stream>>>(W1, W1T, 512, 2048, 1.0f);
  k_wt<<<dim3(64, 16, 1), 256, 0, stream>>>(W2, W2T, 2048, 512, 1.0f);

  k_fin<<<4096, 256, 0, stream>>>(attf, attb, 1048576);

  k_gemm<EPI_RELU><<<dim3(64, 16, 1), 256, 0, stream>>>(
      attb, 0, W1T, 0, 0, b1, hid, nullptr, 512);
  k_gemm<EPI_OUT><<<dim3(64, 4, 1), 256, 0, stream>>>(
      hid, 0, W2T, 0, 0, b2, out, attf, 2048);
}